// Round 18
// baseline (826.835 us; speedup 1.0000x reference)
//
#include <hip/hip_runtime.h>
#include <hip/hip_bf16.h>
#include <stdint.h>

// ---------------------------------------------------------------------------
// AdaptiveAngleConv: 5 angles of (bilinear deform-sample -> 3x3 conv)
// Conv v13: counted-vmcnt pipeline at MAX waves under the 2-block/CU law.
//  - block 128px x 256oc (full oc -> no A duplication), 512 thr / 8 waves
//    (2M x 4N), wave 64x64, BK=32, 72 K-steps tap-inner
//  - LDS = A ring-4 (4x8KB) + B ring-3 (3x16KB) = 80KiB -> 2 blocks/CU,
//    16 waves/CU (2x round-17 TLP)
//  - prefetch: A 3 iters ahead, B 2 iters ahead; gate vmcnt(4) steady,
//    vmcnt(3)/vmcnt(0) tail (FIFO retirement hand-verified)
//  - conflict-free 128B-line layout (2 px per line, round-12-verified)
//  - pair/XCD: bijective chunked swizzle; __launch_bounds__(512,4)
// Sampler: integer-offset fast path (angles 0/90/180 -> single gather).
// ---------------------------------------------------------------------------

#define S2F 1.41421356237309515f

__constant__ float c_ox[5][9] = {
  {0.f,0.f,0.f,0.f,0.f,0.f,0.f,0.f,0.f},
  {1.f-S2F, 1.f-S2F*0.5f, 1.f, -S2F*0.5f, 0.f, S2F*0.5f, -1.f, S2F*0.5f-1.f, S2F-1.f},
  {0.f,1.f,2.f,-1.f,0.f,1.f,-2.f,-1.f,0.f},
  {1.f, 1.f+S2F*0.5f, 1.f+S2F, -S2F*0.5f, 0.f, S2F*0.5f, -1.f-S2F, -1.f-S2F*0.5f, -1.f},
  {2.f,2.f,2.f,0.f,0.f,0.f,-2.f,-2.f,-2.f}
};
__constant__ float c_oy[5][9] = {
  {0.f,0.f,0.f,0.f,0.f,0.f,0.f,0.f,0.f},
  {1.f, S2F*0.5f, S2F-1.f, 1.f-S2F*0.5f, 0.f, S2F*0.5f-1.f, 1.f-S2F, -S2F*0.5f, -1.f},
  {2.f,1.f,0.f,1.f,0.f,-1.f,0.f,-1.f,-2.f},
  {1.f+S2F, S2F*0.5f, -1.f, 1.f+S2F*0.5f, 0.f, -1.f-S2F*0.5f, 1.f, -S2F*0.5f, 1.f+S2F},
  {2.f,0.f,-2.f,2.f,0.f,-2.f,2.f,0.f,-2.f}
};

typedef __bf16 bf16x8_t __attribute__((ext_vector_type(8)));
typedef float f32x4_t __attribute__((ext_vector_type(4)));

typedef const __attribute__((address_space(1))) void* as1cp;
typedef __attribute__((address_space(3))) void* as3p;

__device__ __forceinline__ void gload16(const void* g, void* l) {
  __builtin_amdgcn_global_load_lds((as1cp)g, (as3p)l, 16, 0, 0);
}

// x NCHW (2,256,64,64) -> xT NHWC (2,64,64,256) f32
__global__ void k_transpose(const float* __restrict__ x, float* __restrict__ xT) {
  const int v = blockIdx.x, u = blockIdx.y, b = blockIdx.z;
  const int ic = threadIdx.x;
  xT[(((b*64 + u)*64 + v)*256) + ic] =
      x[(((b*256 + ic)*64 + u)*64) + v];
}

// weight OIHW (256,256,3,3) f32 -> wb (9,256,256)=[t][oc][ic] bf16
__global__ void k_wconv(const float* __restrict__ w, __hip_bfloat16* __restrict__ wb) {
  const int tid = blockIdx.x*256 + threadIdx.x;   // < 9*256*256
  const int t = tid >> 16;
  const int rem = tid & 65535;
  const int oc = rem >> 8;
  const int ic = rem & 255;
  wb[tid] = __float2bfloat16(w[(oc*256 + ic)*9 + t]);
}

// bilinear deform-sample -> xo bf16 NHWC [(a)][b][192][192][256]
__global__ void k_sample(const float* __restrict__ xT,
                         __hip_bfloat16* __restrict__ xo, int a0)
{
  const int aidx = a0 + blockIdx.z;
  __hip_bfloat16* xoa = xo + (size_t)blockIdx.z * (2ull*192*192*256);

  const int tid = threadIdx.x;           // 256
  const int ic = (tid & 63) * 4;
  const int j = blockIdx.x*4 + (tid >> 6);
  const int i = blockIdx.y;

  const int a = i / 3, r = i - 3*a;
  const int bc = j / 3, s = j - 3*bc;
  const int n = r*3 + s;
  const float px = (float)(a + r) + c_ox[aidx][n];
  const float py = (float)(bc + s) + c_oy[aidx][n];
  const float fx = floorf(px), fy = floorf(py);
  const float pxc = fminf(fmaxf(px, 0.f), 65.f);
  const float pyc = fminf(fmaxf(py, 0.f), 65.f);
  const int qlx = (int)fminf(fmaxf(fx,      0.f), 65.f);
  const int qrx = (int)fminf(fmaxf(fx + 1.f, 0.f), 65.f);
  const int qly = (int)fminf(fmaxf(fy,      0.f), 65.f);
  const int qry = (int)fminf(fmaxf(fy + 1.f, 0.f), 65.f);

  const bool inxl = (qlx >= 1) && (qlx <= 64);
  const bool inyl = (qly >= 1) && (qly <= 64);

  const size_t o0 = (((size_t)0*192 + i)*192 + j)*256 + ic;
  const size_t o1 = (((size_t)1*192 + i)*192 + j)*256 + ic;
  const f32x4_t zero = (f32x4_t){0.f,0.f,0.f,0.f};

  if (px == fx && py == fy) {
    #pragma unroll
    for (int b = 0; b < 2; ++b) {
      const float* xb = xT + (size_t)b * (64*64*256);
      f32x4_t v = (inxl && inyl) ? *(const f32x4_t*)&xb[((qlx-1)*64 + (qly-1))*256 + ic] : zero;
      ushort4 pk;
      pk.x = __hip_bfloat16_raw(__float2bfloat16(v[0])).x;
      pk.y = __hip_bfloat16_raw(__float2bfloat16(v[1])).x;
      pk.z = __hip_bfloat16_raw(__float2bfloat16(v[2])).x;
      pk.w = __hip_bfloat16_raw(__float2bfloat16(v[3])).x;
      *(ushort4*)&xoa[b ? o1 : o0] = pk;
    }
    return;
  }

  const float wlx = 1.f + (float)qlx - pxc;
  const float wrx = 1.f - (float)qrx + pxc;
  const float wly = 1.f + (float)qly - pyc;
  const float wry = 1.f - (float)qry + pyc;
  const float glt = wlx*wly, grb = wrx*wry, glb = wlx*wry, grt = wrx*wly;

  const bool inxr = (qrx >= 1) && (qrx <= 64);
  const bool inyr = (qry >= 1) && (qry <= 64);

  #pragma unroll
  for (int b = 0; b < 2; ++b) {
    const float* xb = xT + (size_t)b * (64*64*256);
    f32x4_t vlt = (inxl && inyl) ? *(const f32x4_t*)&xb[((qlx-1)*64 + (qly-1))*256 + ic] : zero;
    f32x4_t vrb = (inxr && inyr) ? *(const f32x4_t*)&xb[((qrx-1)*64 + (qry-1))*256 + ic] : zero;
    f32x4_t vlb = (inxl && inyr) ? *(const f32x4_t*)&xb[((qlx-1)*64 + (qry-1))*256 + ic] : zero;
    f32x4_t vrt = (inxr && inyl) ? *(const f32x4_t*)&xb[((qrx-1)*64 + (qly-1))*256 + ic] : zero;
    ushort4 pk;
    float v0 = glt*vlt[0] + grb*vrb[0] + glb*vlb[0] + grt*vrt[0];
    float v1 = glt*vlt[1] + grb*vrb[1] + glb*vlb[1] + grt*vrt[1];
    float v2 = glt*vlt[2] + grb*vrb[2] + glb*vlb[2] + grt*vrt[2];
    float v3 = glt*vlt[3] + grb*vrb[3] + glb*vlb[3] + grt*vrt[3];
    pk.x = __hip_bfloat16_raw(__float2bfloat16(v0)).x;
    pk.y = __hip_bfloat16_raw(__float2bfloat16(v1)).x;
    pk.z = __hip_bfloat16_raw(__float2bfloat16(v2)).x;
    pk.w = __hip_bfloat16_raw(__float2bfloat16(v3)).x;
    *(ushort4*)&xoa[b ? o1 : o0] = pk;
  }
}

// ---------------------------------------------------------------------------
// conv v13: 1-D grid nZ*285 (bijective XCD chunking). Block 128px x 256oc,
// 512 thr / 8 waves (wm = w>>2 in {0,1}: 64px half; wn = w&3: 64oc quarter).
// K: 72 BK=32 steps, tap-inner (icg = kk/9 of 32 ic, tap = kk%9).
// LDS (dynamic 81920B): A ring-4 @ {0..3}*8192 (128px x 64B as 64 lines x
// 128B, 2px/line); B ring-3 @ 32768 + {0..2}*16384 (256oc x 64B, same).
// Epilogue overlays f32[128][132] (2 oc-half passes).
// ---------------------------------------------------------------------------
__global__ __launch_bounds__(512, 4) void k_conv13(
    const __hip_bfloat16* __restrict__ xo,   // [z][192][192][256] bf16
    const __hip_bfloat16* __restrict__ wb,   // [9][256][256] bf16 (t,oc,ic)
    float* __restrict__ out)                 // + z*9241600 : [256][190][190]
{
  extern __shared__ __align__(16) char smem[];
  const int tid = threadIdx.x;

  const int nblk = gridDim.x;
  const int qq = nblk >> 3, rr = nblk & 7;
  const int xcd = blockIdx.x & 7, pos = blockIdx.x >> 3;
  const int swz = (xcd < rr ? xcd*(qq+1) : rr*(qq+1) + (xcd-rr)*qq) + pos;
  const int z = swz / 285;
  const int rem = swz - z*285;
  const int it = rem / 3, ct = rem - it*3;
  const int i0 = it*2, j0 = ct*64;

  const int w = tid >> 6, l = tid & 63;
  const int l15 = l & 15, lk = l >> 4;
  const int wm = w >> 2, wn = w & 3;

  const char* xob = (const char*)xo + (size_t)z * 18874368u;
  const char* wbc = (const char*)wb;

  // --- staging constants (chunk c -> 2px/line layout, involution s^(line&3)) ---
  const int apx  = ((tid >> 3) << 1) | ((tid >> 2) & 1);   // 0..127
  const int adi  = apx >> 6;
  const int acol = j0 + (apx & 63);
  const int s16  = ((tid & 3) ^ ((tid >> 3) & 3)) * 16;    // ic 16B-slot offset
  const int boc0 = ((tid >> 3) << 1) | ((tid >> 2) & 1);   // 0..127 (+128 for c2)
  const int wofs = w*1024;

  auto stageA = [&](int kk) {
    const int icg = kk / 9, t = kk - icg*9;
    const int ki = t/3, kj = t - 3*ki;
    int col = acol + kj; col = (col > 191) ? 191 : col;     // garbage, never stored
    const int i = i0 + adi + ki;                            // <= 191 always
    gload16(xob + (size_t)((i*192 + col)*512 + icg*64 + s16),
            smem + (kk & 3)*8192 + wofs);
  };
  auto stageB = [&](int kk, int sl) {
    const int icg = kk / 9, t = kk - icg*9;
    const char* src = wbc + (size_t)(t*131072 + icg*64 + s16);
    char* dst = smem + 32768 + sl*16384 + wofs;
    gload16(src + boc0*512,          dst);
    gload16(src + (boc0 + 128)*512,  dst + 8192);
  };

  f32x4_t acc[4][4];
  #pragma unroll
  for (int mf = 0; mf < 4; ++mf)
    #pragma unroll
    for (int nf = 0; nf < 4; ++nf)
      acc[mf][nf] = (f32x4_t){0.f, 0.f, 0.f, 0.f};

  // frag read offsets (round-12-verified conflict-free line layout)
  const int frow = (l15 >> 1)*128 + ((l15 & 1)*4 + (lk ^ ((l15 >> 1) & 3)))*16;
  const int aFB = wm*4096 + frow;          // + slot*8192 + mf*1024
  const int bFB = 32768 + wn*4096 + frow;  // + slot*16384 + nf*1024

  auto compute = [&](int as, int bsl) {
    const char* A = smem + as*8192 + aFB;
    const char* B = smem + bsl*16384 + bFB;
    bf16x8_t af[4], bf[4];
    #pragma unroll
    for (int mf = 0; mf < 4; ++mf) af[mf] = *(const bf16x8_t*)(A + mf*1024);
    #pragma unroll
    for (int nf = 0; nf < 4; ++nf) bf[nf] = *(const bf16x8_t*)(B + nf*1024);
    #pragma unroll
    for (int mf = 0; mf < 4; ++mf)
      #pragma unroll
      for (int nf = 0; nf < 4; ++nf)
        acc[mf][nf] = __builtin_amdgcn_mfma_f32_16x16x32_bf16(
            af[mf], bf[nf], acc[mf][nf], 0, 0, 0);
  };

  // prologue: A0,B0,A1,B1,A2 (7 loads); gate leaves A1,B1x2,A2 in flight
  stageA(0); stageB(0, 0); stageA(1); stageB(1, 1); stageA(2);
  asm volatile("s_waitcnt vmcnt(4)" ::: "memory");
  __builtin_amdgcn_s_barrier();

  int bs = 0, bsS = 2;   // compute B slot kk%3; stage B slot (kk+2)%3
  for (int kk = 0; kk < 72; ++kk) {
    if (kk < 70) stageB(kk + 2, bsS);
    if (kk < 69) stageA(kk + 3);
    compute(kk & 3, bs);
    if (kk < 69)       { asm volatile("s_waitcnt vmcnt(4)" ::: "memory");
                         __builtin_amdgcn_s_barrier(); }
    else if (kk == 69) { asm volatile("s_waitcnt vmcnt(3)" ::: "memory");
                         __builtin_amdgcn_s_barrier(); }
    else if (kk == 70) { asm volatile("s_waitcnt vmcnt(0)" ::: "memory");
                         __builtin_amdgcn_s_barrier(); }
    bs  = (bs  == 2) ? 0 : bs  + 1;
    bsS = (bsS == 2) ? 0 : bsS + 1;
  }

  // --- epilogue: 2 oc-half passes via eps f32[128][132] (67584 B) ---
  float* eps = (float*)smem;
  float* outb = out + (size_t)z * 9241600u;
  const int ocr = tid >> 2, q = tid & 3;
  const int iS = i0 + (q >> 1);                    // <= 189 always
  const int jb = j0 + (q & 1)*32;
  const int kmax = (ct == 2 && (q & 1)) ? 30 : 32;

  #pragma unroll
  for (int h = 0; h < 2; ++h) {
    __syncthreads();
    if ((wn >> 1) == h) {
      #pragma unroll
      for (int mf = 0; mf < 4; ++mf)
        #pragma unroll
        for (int nf = 0; nf < 4; ++nf)
          #pragma unroll
          for (int r = 0; r < 4; ++r)
            eps[((wn & 1)*64 + nf*16 + l15)*132 + wm*64 + mf*16 + lk*4 + r] =
                acc[mf][nf][r];
    }
    __syncthreads();
    {
      float* dst = outb + (size_t)(h*128 + ocr)*36100u + iS*190 + jb;
      const float* src = eps + ocr*132 + q*32;
      for (int k = 0; k < kmax; k += 2)
        *(float2*)(dst + k) = make_float2(src[k], src[k + 1]);
    }
  }
}

extern "C" void kernel_launch(void* const* d_in, const int* in_sizes, int n_in,
                              void* d_out, int out_size, void* d_ws, size_t ws_size,
                              hipStream_t stream)
{
  const float* x = (const float*)d_in[0];
  const float* w = (const float*)d_in[1];
  float* out = (float*)d_out;

  char* ws = (char*)d_ws;
  float*          xT = (float*)ws;                         // 8,388,608 B
  __hip_bfloat16* wb = (__hip_bfloat16*)(ws + 8388608);    // 1,179,648 B
  __hip_bfloat16* xo = (__hip_bfloat16*)(ws + 9568256);    // 5 or 1 x 37,748,736 B

  const bool merged = (ws_size >= 198311936ull);

  (void)hipFuncSetAttribute((const void*)k_conv13,
                            hipFuncAttributeMaxDynamicSharedMemorySize, 81920);

  k_transpose<<<dim3(64, 64, 2), 256, 0, stream>>>(x, xT);
  k_wconv<<<2304, 256, 0, stream>>>(w, wb);

  if (merged) {
    k_sample<<<dim3(48, 192, 5), 256, 0, stream>>>(xT, xo, 0);
    k_conv13<<<2850, 512, 81920, stream>>>(xo, wb, out);
  } else {
    for (int aidx = 0; aidx < 5; ++aidx) {
      k_sample<<<dim3(48, 192, 1), 256, 0, stream>>>(xT, xo, aidx);
      k_conv13<<<570, 512, 81920, stream>>>(xo, wb, out + (size_t)aidx * 18483200u);
    }
  }
}

// Round 19
// 509.945 us; speedup vs baseline: 1.6214x; 1.6214x over previous
//
#include <hip/hip_runtime.h>
#include <hip/hip_bf16.h>
#include <stdint.h>

// ---------------------------------------------------------------------------
// AdaptiveAngleConv: 5 angles of (bilinear deform-sample -> 3x3 conv)
// x: (2,256,64,64) f32, weight: (256,256,3,3) f32
// out: 5 x (2,256,190,190) f32 concatenated
// FINAL (round-17 consolidation): conv = m97 structure, 128x128, BK=64,
// tap-inner, pair-XCD swizzle, A ring-3 + B dbuf-2 = 80KiB (2 blocks/CU),
// counted vmcnt(4) + raw barrier (never drains newest A prefetch).
// 924 TF measured. Sampler: integer-offset fast path.
// ---------------------------------------------------------------------------

#define S2F 1.41421356237309515f

__constant__ float c_ox[5][9] = {
  {0.f,0.f,0.f,0.f,0.f,0.f,0.f,0.f,0.f},
  {1.f-S2F, 1.f-S2F*0.5f, 1.f, -S2F*0.5f, 0.f, S2F*0.5f, -1.f, S2F*0.5f-1.f, S2F-1.f},
  {0.f,1.f,2.f,-1.f,0.f,1.f,-2.f,-1.f,0.f},
  {1.f, 1.f+S2F*0.5f, 1.f+S2F, -S2F*0.5f, 0.f, S2F*0.5f, -1.f-S2F, -1.f-S2F*0.5f, -1.f},
  {2.f,2.f,2.f,0.f,0.f,0.f,-2.f,-2.f,-2.f}
};
__constant__ float c_oy[5][9] = {
  {0.f,0.f,0.f,0.f,0.f,0.f,0.f,0.f,0.f},
  {1.f, S2F*0.5f, S2F-1.f, 1.f-S2F*0.5f, 0.f, S2F*0.5f-1.f, 1.f-S2F, -S2F*0.5f, -1.f},
  {2.f,1.f,0.f,1.f,0.f,-1.f,0.f,-1.f,-2.f},
  {1.f+S2F, S2F*0.5f, -1.f, 1.f+S2F*0.5f, 0.f, -1.f-S2F*0.5f, 1.f, -S2F*0.5f, 1.f+S2F},
  {2.f,0.f,-2.f,2.f,0.f,-2.f,2.f,0.f,-2.f}
};

typedef __bf16 bf16x8_t __attribute__((ext_vector_type(8)));
typedef float f32x4_t __attribute__((ext_vector_type(4)));

typedef const __attribute__((address_space(1))) void* as1cp;
typedef __attribute__((address_space(3))) void* as3p;

__device__ __forceinline__ void gload16(const void* g, void* l) {
  __builtin_amdgcn_global_load_lds((as1cp)g, (as3p)l, 16, 0, 0);
}

// x NCHW (2,256,64,64) -> xT NHWC (2,64,64,256) f32
__global__ void k_transpose(const float* __restrict__ x, float* __restrict__ xT) {
  const int v = blockIdx.x, u = blockIdx.y, b = blockIdx.z;
  const int ic = threadIdx.x;
  xT[(((b*64 + u)*64 + v)*256) + ic] =
      x[(((b*256 + ic)*64 + u)*64) + v];
}

// weight OIHW (256,256,3,3) f32 -> wb (9,256,256)=[t][oc][ic] bf16
__global__ void k_wconv(const float* __restrict__ w, __hip_bfloat16* __restrict__ wb) {
  const int tid = blockIdx.x*256 + threadIdx.x;   // < 9*256*256
  const int t = tid >> 16;
  const int rem = tid & 65535;
  const int oc = rem >> 8;
  const int ic = rem & 255;
  wb[tid] = __float2bfloat16(w[(oc*256 + ic)*9 + t]);
}

// bilinear deform-sample -> xo bf16 NHWC [(a)][b][192][192][256]
__global__ void k_sample(const float* __restrict__ xT,
                         __hip_bfloat16* __restrict__ xo, int a0)
{
  const int aidx = a0 + blockIdx.z;
  __hip_bfloat16* xoa = xo + (size_t)blockIdx.z * (2ull*192*192*256);

  const int tid = threadIdx.x;           // 256
  const int ic = (tid & 63) * 4;
  const int j = blockIdx.x*4 + (tid >> 6);
  const int i = blockIdx.y;

  const int a = i / 3, r = i - 3*a;
  const int bc = j / 3, s = j - 3*bc;
  const int n = r*3 + s;
  const float px = (float)(a + r) + c_ox[aidx][n];
  const float py = (float)(bc + s) + c_oy[aidx][n];
  const float fx = floorf(px), fy = floorf(py);
  const float pxc = fminf(fmaxf(px, 0.f), 65.f);
  const float pyc = fminf(fmaxf(py, 0.f), 65.f);
  const int qlx = (int)fminf(fmaxf(fx,      0.f), 65.f);
  const int qrx = (int)fminf(fmaxf(fx + 1.f, 0.f), 65.f);
  const int qly = (int)fminf(fmaxf(fy,      0.f), 65.f);
  const int qry = (int)fminf(fmaxf(fy + 1.f, 0.f), 65.f);

  const bool inxl = (qlx >= 1) && (qlx <= 64);
  const bool inyl = (qly >= 1) && (qly <= 64);

  const size_t o0 = (((size_t)0*192 + i)*192 + j)*256 + ic;
  const size_t o1 = (((size_t)1*192 + i)*192 + j)*256 + ic;
  const f32x4_t zero = (f32x4_t){0.f,0.f,0.f,0.f};

  if (px == fx && py == fy) {
    #pragma unroll
    for (int b = 0; b < 2; ++b) {
      const float* xb = xT + (size_t)b * (64*64*256);
      f32x4_t v = (inxl && inyl) ? *(const f32x4_t*)&xb[((qlx-1)*64 + (qly-1))*256 + ic] : zero;
      ushort4 pk;
      pk.x = __hip_bfloat16_raw(__float2bfloat16(v[0])).x;
      pk.y = __hip_bfloat16_raw(__float2bfloat16(v[1])).x;
      pk.z = __hip_bfloat16_raw(__float2bfloat16(v[2])).x;
      pk.w = __hip_bfloat16_raw(__float2bfloat16(v[3])).x;
      *(ushort4*)&xoa[b ? o1 : o0] = pk;
    }
    return;
  }

  const float wlx = 1.f + (float)qlx - pxc;
  const float wrx = 1.f - (float)qrx + pxc;
  const float wly = 1.f + (float)qly - pyc;
  const float wry = 1.f - (float)qry + pyc;
  const float glt = wlx*wly, grb = wrx*wry, glb = wlx*wry, grt = wrx*wly;

  const bool inxr = (qrx >= 1) && (qrx <= 64);
  const bool inyr = (qry >= 1) && (qry <= 64);

  #pragma unroll
  for (int b = 0; b < 2; ++b) {
    const float* xb = xT + (size_t)b * (64*64*256);
    f32x4_t vlt = (inxl && inyl) ? *(const f32x4_t*)&xb[((qlx-1)*64 + (qly-1))*256 + ic] : zero;
    f32x4_t vrb = (inxr && inyr) ? *(const f32x4_t*)&xb[((qrx-1)*64 + (qry-1))*256 + ic] : zero;
    f32x4_t vlb = (inxl && inyr) ? *(const f32x4_t*)&xb[((qlx-1)*64 + (qry-1))*256 + ic] : zero;
    f32x4_t vrt = (inxr && inyl) ? *(const f32x4_t*)&xb[((qrx-1)*64 + (qly-1))*256 + ic] : zero;
    ushort4 pk;
    float v0 = glt*vlt[0] + grb*vrb[0] + glb*vlb[0] + grt*vrt[0];
    float v1 = glt*vlt[1] + grb*vrb[1] + glb*vlb[1] + grt*vrt[1];
    float v2 = glt*vlt[2] + grb*vrb[2] + glb*vlb[2] + grt*vrt[2];
    float v3 = glt*vlt[3] + grb*vrb[3] + glb*vlb[3] + grt*vrt[3];
    pk.x = __hip_bfloat16_raw(__float2bfloat16(v0)).x;
    pk.y = __hip_bfloat16_raw(__float2bfloat16(v1)).x;
    pk.z = __hip_bfloat16_raw(__float2bfloat16(v2)).x;
    pk.w = __hip_bfloat16_raw(__float2bfloat16(v3)).x;
    *(ushort4*)&xoa[b ? o1 : o0] = pk;
  }
}

// implicit-GEMM conv: M=128 px, N=128 oc, K=9 taps x 256 ic (36 BK=64 tiles,
// tap-inner). LDS (dynamic 81920B): A ring-3 @ {0,16384,32768},
// B dbuf-2 @ 49152 + {0,16384}. Loop: stageB(kk+1), stageA(kk+2),
// compute(kk), vmcnt(4)+s_barrier. Epilogue overlays f32[128][129].
__global__ __launch_bounds__(256, 2) void k_conv(
    const __hip_bfloat16* __restrict__ xo,   // [z][192][192][256] bf16
    const __hip_bfloat16* __restrict__ wb,   // [9][256][256] bf16 (t,oc,ic)
    float* __restrict__ out)                 // + z*9241600 : [256][190][190]
{
  extern __shared__ __align__(16) char smem[];
  const int tid = threadIdx.x;

  // --- pair-preserving swizzle decode (bijective; tail of <16 linear) ---
  const int f = blockIdx.x;
  const int T = gridDim.x & ~15;
  int pairI, nt;
  if (f < T) { pairI = (f >> 4)*8 + (f & 7); nt = (f >> 3) & 1; }
  else       { pairI = (T >> 1) + ((f - T) >> 1); nt = f & 1; }
  const int ct = pairI % 3;
  const int yz = pairI / 3;
  const int i0 = (yz % 95) * 2;
  const int z  = yz / 95;
  const int oc0 = nt * 128;
  const int j0 = ct * 64;

  const int q8   = tid >> 3;           // 0..31
  const int slot = tid & 7;
  const int wv   = tid >> 6;           // wave 0..3
  const int sw   = slot ^ (q8 & 7);    // XOR-swizzled 16B slot (pre-swizzle source)

  const char* xob = (const char*)xo + (size_t)z * 18874368u;
  const char* wbc = (const char*)wb;

  int arow[4], acol[4], brow[4];
  #pragma unroll
  for (int p = 0; p < 4; ++p) {
    const int m = p*32 + q8;
    arow[p] = i0 + (m >> 6);
    acol[p] = j0 + (m & 63);
    brow[p] = oc0 + m;
  }

  f32x4_t acc[4][4];
  #pragma unroll
  for (int fm = 0; fm < 4; ++fm)
    #pragma unroll
    for (int fn = 0; fn < 4; ++fn)
      acc[fm][fn] = (f32x4_t){0.f, 0.f, 0.f, 0.f};

  const int lane = tid & 63;
  const int lrow = lane & 15;
  const int lk   = lane >> 4;
  const int wm   = wv >> 1;
  const int wn   = wv & 1;

  auto stageA = [&](int kk, int s) {
    const int icg = kk / 9;
    const int t   = kk - icg*9;
    const int ki = t / 3, kj = t - 3*ki;
    char* sa = smem + s*16384 + wv*1024;
    #pragma unroll
    for (int p = 0; p < 4; ++p) {
      int col = acol[p] + kj; col = (col > 191) ? 191 : col;   // garbage, never stored
      const char* ga = xob + (((arow[p] + ki)*192 + col)*256 + icg*64)*2 + sw*16;
      gload16(ga, sa + p*4096);
    }
  };
  auto stageB = [&](int kk, int b) {
    const int icg = kk / 9;
    const int t   = kk - icg*9;
    char* sb = smem + 49152 + b*16384 + wv*1024;
    #pragma unroll
    for (int p = 0; p < 4; ++p) {
      const char* gb = wbc + ((t*256 + brow[p])*256 + icg*64)*2 + sw*16;
      gload16(gb, sb + p*4096);
    }
  };

  auto compute = [&](int s, int b) {
    const char* sa = smem + s*16384;
    const char* sb = smem + 49152 + b*16384;
    bf16x8_t af[4][2], bfr[4][2];
    #pragma unroll
    for (int fi = 0; fi < 4; ++fi) {
      const int m = wm*64 + fi*16 + lrow;
      const int n = wn*64 + fi*16 + lrow;
      #pragma unroll
      for (int ks = 0; ks < 2; ++ks) {
        af[fi][ks]  = *(const bf16x8_t*)(sa + m*128 + (((ks*4 + lk) ^ (m & 7)) * 16));
        bfr[fi][ks] = *(const bf16x8_t*)(sb + n*128 + (((ks*4 + lk) ^ (n & 7)) * 16));
      }
    }
    #pragma unroll
    for (int fm = 0; fm < 4; ++fm)
      #pragma unroll
      for (int fn = 0; fn < 4; ++fn)
        #pragma unroll
        for (int ks = 0; ks < 2; ++ks)
          acc[fm][fn] = __builtin_amdgcn_mfma_f32_16x16x32_bf16(
              af[fm][ks], bfr[fn][ks], acc[fm][fn], 0, 0, 0);
  };

  // prologue: A0, B0, A1 staged; wait A0+B0 (leave A1's 4 in flight)
  stageA(0, 0);
  stageB(0, 0);
  stageA(1, 1);
  asm volatile("s_waitcnt vmcnt(4)" ::: "memory");
  __builtin_amdgcn_s_barrier();

  int cs = 0, ss = 2;                      // compute slot kk%3; stage slot (kk+2)%3
  for (int kk = 0; kk < 36; ++kk) {
    if (kk < 35) stageB(kk + 1, (kk + 1) & 1);
    if (kk < 34) stageA(kk + 2, ss);
    compute(cs, kk & 1);
    if (kk < 34)       { asm volatile("s_waitcnt vmcnt(4)" ::: "memory");
                         __builtin_amdgcn_s_barrier(); }
    else if (kk == 34) { asm volatile("s_waitcnt vmcnt(0)" ::: "memory");
                         __builtin_amdgcn_s_barrier(); }
    cs = (cs == 2) ? 0 : cs + 1;
    ss = (ss == 2) ? 0 : ss + 1;
  }

  // epilogue: LDS transpose to [oc'][m'] (pad 129) for coalesced NCHW stores
  __syncthreads();
  float* eps = (float*)smem;
  #pragma unroll
  for (int fm = 0; fm < 4; ++fm)
    #pragma unroll
    for (int fn = 0; fn < 4; ++fn)
      #pragma unroll
      for (int r = 0; r < 4; ++r)
        eps[(wn*64 + fn*16 + lrow)*129 + (wm*64 + fm*16 + lk*4 + r)] = acc[fm][fn][r];
  __syncthreads();

  float* outb = out + (size_t)z * 9241600u;
  #pragma unroll
  for (int pass = 0; pass < 16; ++pass) {
    const int ocw = pass*8 + (tid >> 5);
    const int m4  = (tid & 31) * 4;
    const int di  = m4 >> 6, jc = m4 & 63;
    const int i = i0 + di, j = j0 + jc;
    const float v0 = eps[ocw*129 + m4 + 0];
    const float v1 = eps[ocw*129 + m4 + 1];
    const float v2 = eps[ocw*129 + m4 + 2];
    const float v3 = eps[ocw*129 + m4 + 3];
    float* dst = outb + ((size_t)(oc0 + ocw)*190 + i)*190 + j;
    if (j + 3 < 190) {
      *(float2*)dst       = make_float2(v0, v1);   // 8B-aligned always
      *(float2*)(dst + 2) = make_float2(v2, v3);
    } else {
      if (j     < 190) dst[0] = v0;
      if (j + 1 < 190) dst[1] = v1;
      if (j + 2 < 190) dst[2] = v2;
      if (j + 3 < 190) dst[3] = v3;
    }
  }
}

extern "C" void kernel_launch(void* const* d_in, const int* in_sizes, int n_in,
                              void* d_out, int out_size, void* d_ws, size_t ws_size,
                              hipStream_t stream)
{
  const float* x = (const float*)d_in[0];
  const float* w = (const float*)d_in[1];
  float* out = (float*)d_out;

  char* ws = (char*)d_ws;
  float*          xT = (float*)ws;                         // 8,388,608 B
  __hip_bfloat16* wb = (__hip_bfloat16*)(ws + 8388608);    // 1,179,648 B
  __hip_bfloat16* xo = (__hip_bfloat16*)(ws + 9568256);    // 5 or 1 x 37,748,736 B

  const bool merged = (ws_size >= 198311936ull);

  (void)hipFuncSetAttribute((const void*)k_conv,
                            hipFuncAttributeMaxDynamicSharedMemorySize, 81920);

  k_transpose<<<dim3(64, 64, 2), 256, 0, stream>>>(x, xT);
  k_wconv<<<2304, 256, 0, stream>>>(w, wb);

  if (merged) {
    k_sample<<<dim3(48, 192, 5), 256, 0, stream>>>(xT, xo, 0);
    k_conv<<<5700, 256, 81920, stream>>>(xo, wb, out);
  } else {
    for (int aidx = 0; aidx < 5; ++aidx) {
      k_sample<<<dim3(48, 192, 1), 256, 0, stream>>>(xT, xo, aidx);
      k_conv<<<1140, 256, 81920, stream>>>(xo, wb, out + (size_t)aidx * 18483200u);
    }
  }
}